// Round 1
// baseline (475.463 us; speedup 1.0000x reference)
//
#include <hip/hip_runtime.h>
#include <hip/hip_bf16.h>

#define B_  4
#define T_  2048
#define C_  1024
#define NH_ 16
#define HD_ 64

using bf16 = __hip_bfloat16;
typedef __attribute__((ext_vector_type(8))) short bf16x8;   // 8 bf16 = 4 VGPRs (guide-verified frag type)
typedef __attribute__((ext_vector_type(4))) float f32x4;

__device__ __forceinline__ bf16 f2b(float f){ return __float2bfloat16(f); }

// ---------------- conversion kernels ----------------

__global__ __launch_bounds__(256) void k_cvt4(const float* __restrict__ in, bf16* __restrict__ out, int n){
  int i = (blockIdx.x * 256 + threadIdx.x) * 4;
  if (i < n){
    float4 f = *(const float4*)(in + i);
    bf16 b0 = f2b(f.x), b1 = f2b(f.y), b2 = f2b(f.z), b3 = f2b(f.w);
    ushort4 u;
    u.x = *(const unsigned short*)&b0;
    u.y = *(const unsigned short*)&b1;
    u.z = *(const unsigned short*)&b2;
    u.w = *(const unsigned short*)&b3;
    *(ushort4*)(out + i) = u;
  }
}

// in [R][Cc] fp32  ->  out [Cc][R] bf16   (i.e. out[n][k] = in[k][n])
__global__ __launch_bounds__(256) void k_cvtT(const float* __restrict__ in, bf16* __restrict__ out, int R, int Cc){
  int i = blockIdx.x * 256 + threadIdx.x;
  if (i < R * Cc){
    int n = i / R;
    int k = i % R;
    out[i] = f2b(in[k * Cc + n]);
  }
}

// ---------------- GEMM: C[M,N] = A[M,K] * B[K,N] + bias, A row-major bf16, BT = B^T row-major bf16 ----------------
// MODE 0: scatter into Q[B,NH,T,HD], K[B,NH,T,HD], Vt[B,NH,HD,T] (bf16)
// MODE 1: fp32 row-major output
template<int MODE>
__global__ __launch_bounds__(256) void k_gemm(
    const bf16* __restrict__ A, const bf16* __restrict__ BT,
    const float* __restrict__ bias,
    bf16* __restrict__ qo, bf16* __restrict__ ko, bf16* __restrict__ vo,
    float* __restrict__ fout,
    int M, int N, int K)
{
  __shared__ bf16 As[128][40];   // stride 40 bf16 = 20 dwords -> 2-way bank alias (free)
  __shared__ bf16 Bs[128][40];

  const int tid  = threadIdx.x;
  const int wave = tid >> 6, lane = tid & 63;
  const int wm = wave & 1, wn = wave >> 1;
  const int quad = lane >> 4, l15 = lane & 15;
  const int bm = blockIdx.x * 128;
  const int bn = blockIdx.y * 128;

  f32x4 acc[4][4];
  #pragma unroll
  for (int i = 0; i < 4; i++)
    #pragma unroll
    for (int j = 0; j < 4; j++)
      acc[i][j] = (f32x4){0.f, 0.f, 0.f, 0.f};

  for (int k0 = 0; k0 < K; k0 += 32){
    __syncthreads();
    #pragma unroll
    for (int s = 0; s < 2; s++){
      int c = tid + s * 256;            // 512 chunks of 8 bf16 per tile
      int row = c >> 2, col = (c & 3) * 8;
      *(float4*)(&As[row][col]) = *(const float4*)(A  + (size_t)(bm + row) * K + k0 + col);
      *(float4*)(&Bs[row][col]) = *(const float4*)(BT + (size_t)(bn + row) * K + k0 + col);
    }
    __syncthreads();

    bf16x8 af[4], bf[4];
    #pragma unroll
    for (int i = 0; i < 4; i++) af[i] = *reinterpret_cast<const bf16x8*>(&As[wm*64 + i*16 + l15][quad*8]);
    #pragma unroll
    for (int j = 0; j < 4; j++) bf[j] = *reinterpret_cast<const bf16x8*>(&Bs[wn*64 + j*16 + l15][quad*8]);
    #pragma unroll
    for (int i = 0; i < 4; i++)
      #pragma unroll
      for (int j = 0; j < 4; j++)
        acc[i][j] = __builtin_amdgcn_mfma_f32_16x16x32_bf16(af[i], bf[j], acc[i][j], 0, 0, 0);
  }

  // epilogue: C/D layout row = quad*4 + reg, col = lane&15  [verified m89/m91]
  #pragma unroll
  for (int i = 0; i < 4; i++){
    #pragma unroll
    for (int j = 0; j < 4; j++){
      #pragma unroll
      for (int r = 0; r < 4; r++){
        int m = bm + wm*64 + i*16 + quad*4 + r;
        int n = bn + wn*64 + j*16 + l15;
        float v = acc[i][j][r] + bias[n];
        if (MODE == 0){
          int bb = m >> 11, t = m & (T_ - 1);
          int sec = n >> 10, hn = (n & 1023) >> 6, d = n & 63;
          size_t bh = (size_t)(bb * NH_ + hn);
          if      (sec == 0) qo[(bh * T_  + t) * HD_ + d] = f2b(v);
          else if (sec == 1) ko[(bh * T_  + t) * HD_ + d] = f2b(v);
          else               vo[(bh * HD_ + d) * T_  + t] = f2b(v);
        } else {
          fout[(size_t)m * N + n] = v;
        }
      }
    }
  }
}

// ---------------- flash attention (causal), bf16 in/out, fp32 online softmax ----------------
// grid: (T/128, B*NH), 256 threads. Q-tile 128 rows, K/V-tile 64 rows.
__global__ __launch_bounds__(256) void k_attn(
    const bf16* __restrict__ Q, const bf16* __restrict__ Kg,
    const bf16* __restrict__ Vt, bf16* __restrict__ Y)
{
  __shared__ bf16 Qs[128][72];   // [q][d], pad 72 -> 2-way bank alias
  __shared__ bf16 Ks[64][72];    // [krow][d]
  __shared__ bf16 Vs[64][72];    // [d][krow]  (from V^T global)
  __shared__ bf16 Ps[128][72];   // [q][krow]

  const int qt = blockIdx.x;      // 0..15
  const int bh = blockIdx.y;      // 0..63
  const int bb = bh >> 4, hh = bh & 15;
  const int tid  = threadIdx.x;
  const int wave = tid >> 6, lane = tid & 63;
  const int quad = lane >> 4, l15 = lane & 15;

  const size_t baseQK = (size_t)bh * T_ * HD_;
  const size_t baseV  = (size_t)bh * HD_ * T_;

  // stage Q tile [128][64]
  #pragma unroll
  for (int s = 0; s < 4; s++){
    int c = tid + s * 256;
    int row = c >> 3, col = (c & 7) * 8;
    *(float4*)(&Qs[row][col]) = *(const float4*)(Q + baseQK + (size_t)(qt*128 + row) * HD_ + col);
  }

  float m_i[2][4], l_i[2][4];
  f32x4 o[2][4];
  #pragma unroll
  for (int tm = 0; tm < 2; tm++)
    #pragma unroll
    for (int r = 0; r < 4; r++){ m_i[tm][r] = -1e30f; l_i[tm][r] = 0.f; }
  #pragma unroll
  for (int tm = 0; tm < 2; tm++)
    #pragma unroll
    for (int tn = 0; tn < 4; tn++)
      o[tm][tn] = (f32x4){0.f, 0.f, 0.f, 0.f};

  const float scale = 0.125f;   // 1/sqrt(64)
  const int jmax = 2 * qt + 1;

  for (int j = 0; j <= jmax; j++){
    __syncthreads();   // prev PV reads done (also covers initial Q stage before first use)
    // stage K [64][64] and V^T slab [64 d][64 krow]
    #pragma unroll
    for (int s = 0; s < 2; s++){
      int c = tid + s * 256;
      int row = c >> 3, col = (c & 7) * 8;
      *(float4*)(&Ks[row][col]) = *(const float4*)(Kg + baseQK + (size_t)(j*64 + row) * HD_ + col);
      *(float4*)(&Vs[row][col]) = *(const float4*)(Vt + baseV  + (size_t)row * T_ + j*64 + col);
    }
    __syncthreads();

    // S = Q K^T : wave covers rows [wave*32, wave*32+32), all 64 cols
    f32x4 sa[2][4];
    #pragma unroll
    for (int tm = 0; tm < 2; tm++)
      #pragma unroll
      for (int tn = 0; tn < 4; tn++)
        sa[tm][tn] = (f32x4){0.f, 0.f, 0.f, 0.f};

    #pragma unroll
    for (int ks = 0; ks < 2; ks++){
      bf16x8 aq[2], bk[4];
      #pragma unroll
      for (int tm = 0; tm < 2; tm++) aq[tm] = *reinterpret_cast<const bf16x8*>(&Qs[wave*32 + tm*16 + l15][ks*32 + quad*8]);
      #pragma unroll
      for (int tn = 0; tn < 4; tn++) bk[tn] = *reinterpret_cast<const bf16x8*>(&Ks[tn*16 + l15][ks*32 + quad*8]);
      #pragma unroll
      for (int tm = 0; tm < 2; tm++)
        #pragma unroll
        for (int tn = 0; tn < 4; tn++)
          sa[tm][tn] = __builtin_amdgcn_mfma_f32_16x16x32_bf16(aq[tm], bk[tn], sa[tm][tn], 0, 0, 0);
    }

    // mask + online softmax. Row r of tile lives in lanes quad*16 + (0..15): reduce over lane bits 0-3.
    const bool diag = (j >= 2 * qt);
    #pragma unroll
    for (int tm = 0; tm < 2; tm++){
      #pragma unroll
      for (int r = 0; r < 4; r++){
        int rowg = qt*128 + wave*32 + tm*16 + quad*4 + r;
        float mx = -1e30f;
        #pragma unroll
        for (int tn = 0; tn < 4; tn++){
          float sv = sa[tm][tn][r] * scale;
          if (diag){
            int colg = j*64 + tn*16 + l15;
            if (colg > rowg) sv = -1e30f;
          }
          sa[tm][tn][r] = sv;
          mx = fmaxf(mx, sv);
        }
        mx = fmaxf(mx, __shfl_xor(mx, 1, 64));
        mx = fmaxf(mx, __shfl_xor(mx, 2, 64));
        mx = fmaxf(mx, __shfl_xor(mx, 4, 64));
        mx = fmaxf(mx, __shfl_xor(mx, 8, 64));
        float mn = fmaxf(m_i[tm][r], mx);
        float alpha = __expf(m_i[tm][r] - mn);
        m_i[tm][r] = mn;
        float rs = 0.f;
        #pragma unroll
        for (int tn = 0; tn < 4; tn++){
          float pv = __expf(sa[tm][tn][r] - mn);
          sa[tm][tn][r] = pv;
          rs += pv;
        }
        rs += __shfl_xor(rs, 1, 64);
        rs += __shfl_xor(rs, 2, 64);
        rs += __shfl_xor(rs, 4, 64);
        rs += __shfl_xor(rs, 8, 64);
        l_i[tm][r] = l_i[tm][r] * alpha + rs;
        #pragma unroll
        for (int tnd = 0; tnd < 4; tnd++) o[tm][tnd][r] *= alpha;
      }
    }

    // P -> LDS (C/D layout write; A-layout read below)
    #pragma unroll
    for (int tm = 0; tm < 2; tm++)
      #pragma unroll
      for (int tn = 0; tn < 4; tn++)
        #pragma unroll
        for (int r = 0; r < 4; r++)
          Ps[wave*32 + tm*16 + quad*4 + r][tn*16 + l15] = f2b(sa[tm][tn][r]);
    __syncthreads();

    // O += P V
    #pragma unroll
    for (int ks = 0; ks < 2; ks++){
      bf16x8 ap[2], bv[4];
      #pragma unroll
      for (int tm = 0; tm < 2; tm++)  ap[tm]  = *reinterpret_cast<const bf16x8*>(&Ps[wave*32 + tm*16 + l15][ks*32 + quad*8]);
      #pragma unroll
      for (int tnd = 0; tnd < 4; tnd++) bv[tnd] = *reinterpret_cast<const bf16x8*>(&Vs[tnd*16 + l15][ks*32 + quad*8]);
      #pragma unroll
      for (int tm = 0; tm < 2; tm++)
        #pragma unroll
        for (int tnd = 0; tnd < 4; tnd++)
          o[tm][tnd] = __builtin_amdgcn_mfma_f32_16x16x32_bf16(ap[tm], bv[tnd], o[tm][tnd], 0, 0, 0);
    }
  }

  // normalize + write Y[B*T][C] (bf16)
  #pragma unroll
  for (int tm = 0; tm < 2; tm++){
    #pragma unroll
    for (int r = 0; r < 4; r++){
      float inv = 1.0f / l_i[tm][r];
      int t = qt*128 + wave*32 + tm*16 + quad*4 + r;
      #pragma unroll
      for (int tnd = 0; tnd < 4; tnd++){
        int d = tnd*16 + l15;
        Y[((size_t)(bb * T_ + t)) * C_ + hh * HD_ + d] = f2b(o[tm][tnd][r] * inv);
      }
    }
  }
}

// ---------------- launcher ----------------

extern "C" void kernel_launch(void* const* d_in, const int* in_sizes, int n_in,
                              void* d_out, int out_size, void* d_ws, size_t ws_size,
                              hipStream_t stream) {
  const float* x     = (const float*)d_in[0];   // [4,2048,1024]
  const float* Wqkv  = (const float*)d_in[1];   // [1024,3072]
  const float* bqkv  = (const float*)d_in[2];   // [3072]
  const float* Wproj = (const float*)d_in[3];   // [1024,1024]
  const float* bproj = (const float*)d_in[4];   // [1024]
  float* out = (float*)d_out;                   // [4,2048,1024] fp32

  const size_t M = (size_t)B_ * T_;             // 8192
  char* w = (char*)d_ws;
  bf16* xb     = (bf16*)w;  w += M * C_ * 2;                 // 16.8 MB
  bf16* WqkvT  = (bf16*)w;  w += (size_t)3 * C_ * C_ * 2;    //  6.3 MB
  bf16* WprojT = (bf16*)w;  w += (size_t)C_ * C_ * 2;        //  2.1 MB
  bf16* Qb     = (bf16*)w;  w += M * C_ * 2;                 // 16.8 MB
  bf16* Kb     = (bf16*)w;  w += M * C_ * 2;                 // 16.8 MB
  bf16* Vtb    = (bf16*)w;  w += M * C_ * 2;                 // 16.8 MB
  bf16* Yb     = (bf16*)w;  w += M * C_ * 2;                 // 16.8 MB  (total ~93 MB)

  // 1. convert x to bf16
  {
    int n = (int)(M * C_);
    k_cvt4<<<dim3((n/4 + 255)/256), dim3(256), 0, stream>>>(x, xb, n);
  }
  // 2. convert+transpose weights (B^T layout for MFMA b-frag k-contiguity)
  {
    int n = C_ * 3 * C_;
    k_cvtT<<<dim3((n + 255)/256), dim3(256), 0, stream>>>(Wqkv, WqkvT, C_, 3*C_);
  }
  {
    int n = C_ * C_;
    k_cvtT<<<dim3((n + 255)/256), dim3(256), 0, stream>>>(Wproj, WprojT, C_, C_);
  }
  // 3. qkv = x @ Wqkv + bqkv, scattered into Q/K/V^T
  k_gemm<0><<<dim3(M/128, (3*C_)/128), dim3(256), 0, stream>>>(
      xb, WqkvT, bqkv, Qb, Kb, Vtb, nullptr, (int)M, 3*C_, C_);
  // 4. flash attention
  k_attn<<<dim3(T_/128, B_*NH_), dim3(256), 0, stream>>>(Qb, Kb, Vtb, Yb);
  // 5. out = Y @ Wproj + bproj (fp32)
  k_gemm<1><<<dim3(M/128, C_/128), dim3(256), 0, stream>>>(
      Yb, WprojT, bproj, nullptr, nullptr, nullptr, out, (int)M, C_, C_);
}

// Round 2
// 298.171 us; speedup vs baseline: 1.5946x; 1.5946x over previous
//
#include <hip/hip_runtime.h>
#include <hip/hip_bf16.h>

#define B_  4
#define T_  2048
#define C_  1024
#define NH_ 16
#define HD_ 64

using bf16 = __hip_bfloat16;
typedef __attribute__((ext_vector_type(8))) short bf16x8;   // 8 bf16 (4 VGPRs)
typedef __attribute__((ext_vector_type(4))) short bf16x4;   // 4 bf16 (2 VGPRs)
typedef __attribute__((ext_vector_type(4))) float f32x4;

__device__ __forceinline__ bf16 f2b(float f){ return __float2bfloat16(f); }

__device__ __forceinline__ void async_load16(const bf16* g, bf16* l){
  __builtin_amdgcn_global_load_lds((const __attribute__((address_space(1))) unsigned int*)g,
                                   (__attribute__((address_space(3))) unsigned int*)l,
                                   16, 0, 0);
}

// ---------------- conversion kernels ----------------

__global__ __launch_bounds__(256) void k_cvt4(const float* __restrict__ in, bf16* __restrict__ out, int n){
  int i = (blockIdx.x * 256 + threadIdx.x) * 4;
  if (i < n){
    float4 f = *(const float4*)(in + i);
    bf16 b0 = f2b(f.x), b1 = f2b(f.y), b2 = f2b(f.z), b3 = f2b(f.w);
    ushort4 u;
    u.x = *(const unsigned short*)&b0;
    u.y = *(const unsigned short*)&b1;
    u.z = *(const unsigned short*)&b2;
    u.w = *(const unsigned short*)&b3;
    *(ushort4*)(out + i) = u;
  }
}

// in [R][Cc] fp32 -> out [Cc][R] bf16, LDS tile transpose (coalesced read AND write)
__global__ __launch_bounds__(256) void k_cvtT(const float* __restrict__ in, bf16* __restrict__ out, int R, int Cc){
  __shared__ float t[32][33];
  int bx = blockIdx.x * 32;           // col tile (n)
  int by = blockIdx.y * 32;           // row tile (k)
  int lx = threadIdx.x & 31, ly = threadIdx.x >> 5;   // 8 rows per pass
  #pragma unroll
  for (int s = 0; s < 4; s++){
    int k = by + ly + s*8;
    t[ly + s*8][lx] = in[(size_t)k * Cc + bx + lx];
  }
  __syncthreads();
  #pragma unroll
  for (int s = 0; s < 4; s++){
    int n = bx + ly + s*8;
    out[(size_t)n * R + by + lx] = f2b(t[lx][ly + s*8]);
  }
}

// ---------------- GEMM (m97 structure): C[M,N] = A[M,K] * B[K,N] + bias ----------------
// A row-major bf16, BT = B^T row-major bf16. global_load_lds width-16 staging, unpadded LDS.
// MODE 0: scatter into Q(*0.125)[B,NH,T,HD], K[B,NH,T,HD], Vt[B,NH,HD,T] (bf16)
// MODE 1: fp32 row-major output
template<int MODE>
__global__ __launch_bounds__(256) void k_gemm(
    const bf16* __restrict__ A, const bf16* __restrict__ BT,
    const float* __restrict__ bias,
    bf16* __restrict__ qo, bf16* __restrict__ ko, bf16* __restrict__ vo,
    float* __restrict__ fout,
    int M, int N, int K)
{
  __shared__ bf16 As[128][32];   // unpadded: required by global_load_lds contiguity
  __shared__ bf16 Bs[128][32];

  const int tid  = threadIdx.x;
  const int wave = tid >> 6, lane = tid & 63;
  const int wm = wave & 1, wn = wave >> 1;
  const int quad = lane >> 4, l15 = lane & 15;
  const int bm = blockIdx.x * 128;
  const int bn = blockIdx.y * 128;

  // staging: 512 16B-chunks per matrix; chunk c -> row c>>2, col (c&3)*8 elems.
  // instruction (wave, s): LDS dest = base + (s*256 + wave*64)*16 + lane*16 (contiguous).
  const int c0 = wave*64 + lane;
  const int c1 = c0 + 256;
  const bf16* gA0 = A  + (size_t)(bm + (c0>>2))*K + (c0&3)*8;
  const bf16* gA1 = A  + (size_t)(bm + (c1>>2))*K + (c1&3)*8;
  const bf16* gB0 = BT + (size_t)(bn + (c0>>2))*K + (c0&3)*8;
  const bf16* gB1 = BT + (size_t)(bn + (c1>>2))*K + (c1&3)*8;
  bf16* lA0 = &As[0][0] + wave*512;
  bf16* lA1 = &As[0][0] + 2048 + wave*512;
  bf16* lB0 = &Bs[0][0] + wave*512;
  bf16* lB1 = &Bs[0][0] + 2048 + wave*512;

  f32x4 acc[4][4] = {};

  for (int k0 = 0; k0 < K; k0 += 32){
    __syncthreads();                       // prior tile reads done
    async_load16(gA0, lA0); async_load16(gA1, lA1);
    async_load16(gB0, lB0); async_load16(gB1, lB1);
    gA0 += 32; gA1 += 32; gB0 += 32; gB1 += 32;
    __syncthreads();                       // vmcnt(0) drain before barrier -> LDS valid

    bf16x8 af[4], bfv[4];
    #pragma unroll
    for (int i = 0; i < 4; i++) af[i]  = *reinterpret_cast<const bf16x8*>(&As[wm*64 + i*16 + l15][quad*8]);
    #pragma unroll
    for (int j = 0; j < 4; j++) bfv[j] = *reinterpret_cast<const bf16x8*>(&Bs[wn*64 + j*16 + l15][quad*8]);
    #pragma unroll
    for (int i = 0; i < 4; i++)
      #pragma unroll
      for (int j = 0; j < 4; j++)
        acc[i][j] = __builtin_amdgcn_mfma_f32_16x16x32_bf16(af[i], bfv[j], acc[i][j], 0, 0, 0);
  }

  // epilogue: C/D layout row = quad*4 + reg, col = lane&15
  #pragma unroll
  for (int i = 0; i < 4; i++){
    #pragma unroll
    for (int j = 0; j < 4; j++){
      #pragma unroll
      for (int r = 0; r < 4; r++){
        int m = bm + wm*64 + i*16 + quad*4 + r;
        int n = bn + wn*64 + j*16 + l15;
        float v = acc[i][j][r] + bias[n];
        if (MODE == 0){
          int bb = m >> 11, t = m & (T_ - 1);
          int sec = n >> 10, hn = (n & 1023) >> 6, d = n & 63;
          size_t bhx = (size_t)(bb * NH_ + hn);
          if      (sec == 0) qo[(bhx * T_  + t) * HD_ + d] = f2b(v * 0.125f);  // fold 1/sqrt(HD)
          else if (sec == 1) ko[(bhx * T_  + t) * HD_ + d] = f2b(v);
          else               vo[(bhx * HD_ + d) * T_  + t] = f2b(v);
        } else {
          fout[(size_t)m * N + n] = v;
        }
      }
    }
  }
}

// ---------------- flash attention (causal), transposed S^T/O^T scheme ----------------
// grid: (8, B*NH). Block b handles q-tiles {b, 15-b}: 34 KV-iterations each (balanced).
// S^T = K*Q^T so softmax q-index = lane&15 (2 shuffles per reduction); S^T C/D frag
// feeds PV (O^T = V^T * P^T via mfma 16x16x16) directly from registers — no P LDS trip.
__global__ __launch_bounds__(256) void k_attn(
    const bf16* __restrict__ Q, const bf16* __restrict__ Kg,
    const bf16* __restrict__ Vt, bf16* __restrict__ Y)
{
  __shared__ bf16 Qs[128][72];   // [q][d]    pad 72: 2-way bank alias (free)
  __shared__ bf16 Ks[64][72];    // [kv][d]
  __shared__ bf16 Vs[64][72];    // [d][kv]   (from V^T global)

  const int bh = blockIdx.y;
  const int bb = bh >> 4, hh = bh & 15;
  const int tid  = threadIdx.x;
  const int wave = tid >> 6, lane = tid & 63;
  const int quad = lane >> 4, l15 = lane & 15;

  const size_t baseQK = (size_t)bh * T_ * HD_;
  const size_t baseV  = (size_t)bh * HD_ * T_;

  for (int phase = 0; phase < 2; phase++){
    const int qt = phase ? (15 - blockIdx.x) : blockIdx.x;

    __syncthreads();   // previous phase's LDS reads done
    // stage Q tile [128][64] (pre-scaled by 0.125 upstream)
    #pragma unroll
    for (int s = 0; s < 4; s++){
      int c = tid + s*256;
      int row = c >> 3, col = (c & 7) * 8;
      *(float4*)(&Qs[row][col]) = *(const float4*)(Q + baseQK + (size_t)(qt*128 + row)*HD_ + col);
    }

    float m_i[2] = {-1e30f, -1e30f};
    float l_i[2] = {0.f, 0.f};
    f32x4 o[2][4] = {};            // O^T: d = td*16+quad*4+r, q = wave*32+tq*16+l15

    const int jmax = 2*qt + 1;
    for (int j = 0; j <= jmax; j++){
      __syncthreads();             // prev iter reads done (j=0: covers Q stage ordering too)
      #pragma unroll
      for (int s = 0; s < 2; s++){
        int c = tid + s*256;
        int row = c >> 3, col = (c & 7) * 8;
        *(float4*)(&Ks[row][col]) = *(const float4*)(Kg + baseQK + (size_t)(j*64 + row)*HD_ + col);
        *(float4*)(&Vs[row][col]) = *(const float4*)(Vt + baseV  + (size_t)row*T_ + j*64 + col);
      }
      __syncthreads();

      // S^T = K * Q^T. Wave covers q in [wave*32, wave*32+32), all 64 kv rows.
      f32x4 st[2][4] = {};
      #pragma unroll
      for (int ks = 0; ks < 2; ks++){
        bf16x8 qf[2], kf[4];
        #pragma unroll
        for (int tq = 0; tq < 2; tq++) qf[tq] = *reinterpret_cast<const bf16x8*>(&Qs[wave*32 + tq*16 + l15][ks*32 + quad*8]);
        #pragma unroll
        for (int tk = 0; tk < 4; tk++) kf[tk] = *reinterpret_cast<const bf16x8*>(&Ks[tk*16 + l15][ks*32 + quad*8]);
        #pragma unroll
        for (int tq = 0; tq < 2; tq++)
          #pragma unroll
          for (int tk = 0; tk < 4; tk++)
            st[tq][tk] = __builtin_amdgcn_mfma_f32_16x16x32_bf16(kf[tk], qf[tq], st[tq][tk], 0, 0, 0);
      }

      const bool diag = (j >= 2*qt);
      bf16x4 pf[2][4];
      #pragma unroll
      for (int tq = 0; tq < 2; tq++){
        const int qg = qt*128 + wave*32 + tq*16 + l15;
        if (diag){
          #pragma unroll
          for (int tk = 0; tk < 4; tk++){
            const int kvb = j*64 + tk*16 + quad*4;
            #pragma unroll
            for (int r = 0; r < 4; r++)
              if (kvb + r > qg) st[tq][tk][r] = -1e30f;
          }
        }
        float mx = -1e30f;
        #pragma unroll
        for (int tk = 0; tk < 4; tk++)
          #pragma unroll
          for (int r = 0; r < 4; r++) mx = fmaxf(mx, st[tq][tk][r]);
        mx = fmaxf(mx, __shfl_xor(mx, 16, 64));
        mx = fmaxf(mx, __shfl_xor(mx, 32, 64));
        float mn = fmaxf(m_i[tq], mx);
        float alpha = __expf(m_i[tq] - mn);
        m_i[tq] = mn;
        float rs = 0.f;
        #pragma unroll
        for (int tk = 0; tk < 4; tk++){
          bf16x4 pk;
          #pragma unroll
          for (int r = 0; r < 4; r++){
            float p = __expf(st[tq][tk][r] - mn);
            rs += p;
            bf16 pb = f2b(p);
            pk[r] = *(short*)&pb;
          }
          pf[tq][tk] = pk;
        }
        rs += __shfl_xor(rs, 16, 64);
        rs += __shfl_xor(rs, 32, 64);
        l_i[tq] = l_i[tq] * alpha + rs;
        #pragma unroll
        for (int td = 0; td < 4; td++)
          #pragma unroll
          for (int r = 0; r < 4; r++) o[tq][td][r] *= alpha;
      }

      // O^T += V^T * P^T   (16x16x16: A = V^T rows from Vs[d][kv], B = P frag = st C/D regs)
      #pragma unroll
      for (int td = 0; td < 4; td++){
        bf16x4 vf[4];
        #pragma unroll
        for (int tk = 0; tk < 4; tk++)
          vf[tk] = *reinterpret_cast<const bf16x4*>(&Vs[td*16 + l15][tk*16 + quad*4]);
        #pragma unroll
        for (int tq = 0; tq < 2; tq++)
          #pragma unroll
          for (int tk = 0; tk < 4; tk++)
            o[tq][td] = __builtin_amdgcn_mfma_f32_16x16x16bf16_1k(vf[tk], pf[tq][tk], o[tq][td], 0, 0, 0);
      }
    }

    // normalize + write Y[B*T][C]: per (tq,td), 4 consecutive d -> one 8B store
    #pragma unroll
    for (int tq = 0; tq < 2; tq++){
      float inv = 1.0f / l_i[tq];
      int t = qt*128 + wave*32 + tq*16 + l15;
      bf16* yrow = Y + ((size_t)(bb * T_ + t)) * C_ + hh * HD_;
      #pragma unroll
      for (int td = 0; td < 4; td++){
        bf16x4 pk;
        #pragma unroll
        for (int r = 0; r < 4; r++){
          bf16 b = f2b(o[tq][td][r] * inv);
          pk[r] = *(short*)&b;
        }
        *reinterpret_cast<bf16x4*>(yrow + td*16 + quad*4) = pk;
      }
    }
  }
}

// ---------------- launcher ----------------

extern "C" void kernel_launch(void* const* d_in, const int* in_sizes, int n_in,
                              void* d_out, int out_size, void* d_ws, size_t ws_size,
                              hipStream_t stream) {
  const float* x     = (const float*)d_in[0];   // [4,2048,1024]
  const float* Wqkv  = (const float*)d_in[1];   // [1024,3072]
  const float* bqkv  = (const float*)d_in[2];   // [3072]
  const float* Wproj = (const float*)d_in[3];   // [1024,1024]
  const float* bproj = (const float*)d_in[4];   // [1024]
  float* out = (float*)d_out;                   // [4,2048,1024] fp32

  const size_t M = (size_t)B_ * T_;             // 8192
  char* w = (char*)d_ws;
  bf16* xb     = (bf16*)w;  w += M * C_ * 2;
  bf16* WqkvT  = (bf16*)w;  w += (size_t)3 * C_ * C_ * 2;
  bf16* WprojT = (bf16*)w;  w += (size_t)C_ * C_ * 2;
  bf16* Qb     = (bf16*)w;  w += M * C_ * 2;
  bf16* Kb     = (bf16*)w;  w += M * C_ * 2;
  bf16* Vtb    = (bf16*)w;  w += M * C_ * 2;
  bf16* Yb     = (bf16*)w;  w += M * C_ * 2;

  // 1. x -> bf16
  {
    int n = (int)(M * C_);
    k_cvt4<<<dim3((n/4 + 255)/256), dim3(256), 0, stream>>>(x, xb, n);
  }
  // 2. weights -> bf16, transposed (B^T layout)
  k_cvtT<<<dim3((3*C_)/32, C_/32), dim3(256), 0, stream>>>(Wqkv, WqkvT, C_, 3*C_);
  k_cvtT<<<dim3(C_/32, C_/32), dim3(256), 0, stream>>>(Wproj, WprojT, C_, C_);
  // 3. qkv = x @ Wqkv + bqkv  -> Q(scaled)/K/V^T
  k_gemm<0><<<dim3(M/128, (3*C_)/128), dim3(256), 0, stream>>>(
      xb, WqkvT, bqkv, Qb, Kb, Vtb, nullptr, (int)M, 3*C_, C_);
  // 4. flash attention (balanced q-tile pairing)
  k_attn<<<dim3(8, B_*NH_), dim3(256), 0, stream>>>(Qb, Kb, Vtb, Yb);
  // 5. out = Y @ Wproj + bproj (fp32)
  k_gemm<1><<<dim3(M/128, C_/128), dim3(256), 0, stream>>>(
      Yb, WprojT, bproj, nullptr, nullptr, nullptr, out, (int)M, C_, C_);
}